// Round 12
// baseline (592.496 us; speedup 1.0000x reference)
//
#include <hip/hip_runtime.h>
#include <hip/hip_fp16.h>

#define DEVFN __device__ __forceinline__

constexpr int C   = 64;
constexpr int Hh  = 160, Ww = 160, HW = Hh * Ww;   // 25600
constexpr int B   = 2;
constexpr int P   = B * HW;                        // 51200
constexpr int NSET = 32;

// NOTE: __launch_bounds__ on every kernel (round 4: default caps VGPR at 64).
// NOTE-2 (round 5): register arrays must be statically indexed everywhere.
// NOTE-3 (round 6): >~48 uniform floats/iter cannot stream through SGPRs.
// NOTE-4 (round 7): >=4 independent FMA chains per loop body.
// NOTE-5 (round 8): LDS broadcast costs ~12cyc/b128 on the per-CU LDS pipe.
// NOTE-6 (round 9): keep enough waves OR make the loop LDS-bound-aware.
// NOTE-7 (round 10): f16 K-packing halves LDS bytes + inst count.
// NOTE-8 (round 11): LDS-bound broadcast loops scale with px-per-weight-read
// (px_rate = Npx / LDS_cyc_per_iter), nearly independent of occupancy.
// NOTE-9 (round 11): grids of 200 big blocks use only 200/256 CUs with no
// intra-CU overlap; prefer 64-thread single-wave blocks (800+) spread over
// all CUs (~3 resident blocks/CU).

// K1: LayerNorm over channels per pixel
__global__ __launch_bounds__(64, 4) void k1_ln1(
        const float* __restrict__ inp, const float* __restrict__ lnw,
        const float* __restrict__ lnb, float* __restrict__ x1) {
    int p = blockIdx.x * 64 + threadIdx.x;
    int b = p / HW, hw = p % HW;
    const float* src = inp + (size_t)b * C * HW + hw;
    float v[64];
    float s = 0.f, s2 = 0.f;
#pragma unroll
    for (int c = 0; c < 64; c++) {
        float f = src[c * HW];
        v[c] = f; s += f; s2 += f * f;
    }
    float mu  = s * (1.f / 64.f);
    float var = fmaxf(s2 * (1.f / 64.f) - mu * mu, 0.f);
    float r   = rsqrtf(var + 1e-6f);
    float* dst = x1 + (size_t)b * C * HW + hw;
#pragma unroll
    for (int c = 0; c < 64; c++)
        dst[c * HW] = (v[c] - mu) * r * lnw[c] + lnb[c];
}

// K2: spatial mean of x1 per (b,c)
__global__ __launch_bounds__(256) void k2_mean(
        const float* __restrict__ x1, float* __restrict__ meanb) {
    int bc = blockIdx.x;                         // 0..127
    const float* src = x1 + (size_t)bc * HW;
    float s = 0.f;
    for (int i = threadIdx.x; i < HW; i += 256) s += src[i];
#pragma unroll
    for (int o = 32; o > 0; o >>= 1) s += __shfl_down(s, o);
    __shared__ float red[4];
    if ((threadIdx.x & 63) == 0) red[threadIdx.x >> 6] = s;
    __syncthreads();
    if (threadIdx.x == 0)
        meanb[bc] = (red[0] + red[1] + red[2] + red[3]) * (1.f / HW);
}

// K3: sca = sca_w @ mean + sca_b   [B,64]
__global__ __launch_bounds__(256) void k3_sca(
        const float* __restrict__ scaw, const float* __restrict__ scab_,
        const float* __restrict__ meanb, float* __restrict__ sca) {
    int t = threadIdx.x;
    if (t >= 128) return;
    int b = t >> 6, c = t & 63;
    float acc = scab_[c];
#pragma unroll
    for (int k = 0; k < 64; k++)
        acc = fmaf(scaw[c * 64 + k], meanb[b * 64 + k], acc);
    sca[t] = acc;
}

// helper: 3x3 grouped conv taps (groups=32, 2 in-ch per out-ch)
template <bool INT_>
DEVFN void att_taps(const float* __restrict__ xb, int h, int w,
                    const float* c2aw, const float* c2ab, float* t) {
#pragma unroll
    for (int o = 0; o < 32; o++) {
        float acc = c2ab[o];
#pragma unroll
        for (int k = 0; k < 2; k++) {
            const float* xc = xb + (size_t)(2 * o + k) * HW;
            const float* wr = c2aw + (o * 2 + k) * 9;
#pragma unroll
            for (int kh = 0; kh < 3; kh++) {
                int y = h + kh - 1;
#pragma unroll
                for (int kw = 0; kw < 3; kw++) {
                    int x = w + kw - 1;
                    if (INT_ || ((unsigned)y < (unsigned)Hh && (unsigned)x < (unsigned)Ww))
                        acc = fmaf(wr[kh * 3 + kw], xc[y * Ww + x], acc);
                }
            }
        }
        t[o] = acc;
    }
}

// K45: fused k4 (att) + k5 (u1); 64-thread blocks (NOTE-9).
__global__ __launch_bounds__(64, 3) void k45_attu(
        const float* __restrict__ x1, const float* __restrict__ c2aw,
        const float* __restrict__ c2ab, const float* __restrict__ c2bw,
        const float* __restrict__ c2bb, const float* __restrict__ attg,
        const float* __restrict__ c11aw, const float* __restrict__ c11ab,
        float* __restrict__ att, float* __restrict__ u1) {
    __shared__ __half2 W2[2048];
    __shared__ float Wf[1248];
    int tid = threadIdx.x;
    for (int e = tid; e < 2048; e += 64) {
        int cp = e >> 6, co = e & 63;
        W2[e] = __floats2half2_rn(c11aw[co * 64 + 2 * cp],
                                  c11aw[co * 64 + 2 * cp + 1]);
    }
    for (int e = tid; e < 1248; e += 64) {
        float v;
        if (e < 64)        v = c11ab[e];
        else if (e < 640)  v = c2aw[e - 64];
        else if (e < 672)  v = c2ab[e - 640];
        else if (e < 1184) v = c2bw[e - 672];
        else if (e < 1216) v = c2bb[e - 1184];
        else               v = attg[e - 1216];
        Wf[e] = v;
    }
    __syncthreads();

    int p = blockIdx.x * 64 + tid;
    int b = p / HW, hw = p % HW, h = hw / Ww, w = hw % Ww;
    const float* xb = x1 + (size_t)b * C * HW;

    // ---- k4 part ----
    float t[32];
    bool interior = (h >= 1 && h < Hh - 1 && w >= 1 && w < Ww - 1);
    if (interior) att_taps<true>(xb, h, w, &Wf[64], &Wf[640], t);
    else          att_taps<false>(xb, h, w, &Wf[64], &Wf[640], t);
    float g[16];
#pragma unroll
    for (int c = 0; c < 16; c++) g[c] = t[c] * t[c + 16];
    float* adst = att + (size_t)b * NSET * HW + hw;
#pragma unroll 1
    for (int s = 0; s < 32; s++) {
        float acc = Wf[1184 + s];
        const float* wr = &Wf[672 + s * 16];
#pragma unroll
        for (int c = 0; c < 16; c++) acc = fmaf(wr[c], g[c], acc);
        adst[(size_t)s * HW] = acc * Wf[1216 + s];
    }

    // ---- k5 part: half2 K-packed over ci, 64 independent chains ----
    __half2 acc2[64];
#pragma unroll
    for (int co = 0; co < 64; co++) acc2[co] = __floats2half2_rn(0.f, 0.f);
    const float* xc = xb + hw;
#pragma unroll 1
    for (int cp = 0; cp < 32; cp++) {
        float xv0 = xc[(size_t)(2 * cp) * HW];
        float xv1 = xc[(size_t)(2 * cp + 1) * HW];
        __half2 xv2 = __floats2half2_rn(xv0, xv1);
        const __half2* wrow = &W2[cp * 64];
#pragma unroll
        for (int co = 0; co < 64; co++)
            acc2[co] = __hfma2(wrow[co], xv2, acc2[co]);
    }
    float* dst = u1 + (size_t)b * C * HW + hw;
#pragma unroll
    for (int co = 0; co < 64; co++)
        dst[co * HW] = __low2float(acc2[co]) + __high2float(acc2[co]) + Wf[co];
}

// K6: uf = 5x5 grouped conv (groups=16) of u1, pad=2.
// 4 vertically-adjacent px/thread, 1 group/block, weights in LDS.
__global__ __launch_bounds__(128) void k6_uf(
        const float* __restrict__ u1, const float* __restrict__ w,
        const float* __restrict__ bias, float* __restrict__ uf) {
    __shared__ float wsm[404];
    int blk = blockIdx.x;              // 0..1599
    int g   = blk / 100;               // 0..15 uniform
    int ublk = blk % 100;
    int tid = threadIdx.x;
    for (int e = tid; e < 400; e += 128) {
        int o = e / 100, rest = e - o * 100, cl = rest / 25, tp = rest - cl * 25;
        wsm[e] = w[(((g * 4 + o) * 4) + cl) * 25 + tp];
    }
    if (tid < 4) wsm[400 + tid] = bias[g * 4 + tid];
    __syncthreads();

    int unit = ublk * 128 + tid;       // 0..12799 (4-px column units)
    int b  = unit / (HW / 4);
    int rr = unit - b * (HW / 4);
    int r4 = rr / Ww, w_ = rr - r4 * Ww;
    int hA = r4 * 4;
    int hw0 = hA * Ww + w_;
    bool interior = (w_ >= 2 && w_ < Ww - 2 && r4 >= 1 && r4 <= 38);

    float acc[16];                     // [px][o]
#pragma unroll
    for (int i = 0; i < 16; i++) acc[i] = wsm[400 + (i & 3)];

#pragma unroll 1
    for (int cl = 0; cl < 4; cl++) {
        const float* src = u1 + (size_t)(b * C + g * 4 + cl) * HW;
        float tv[40];                  // rows hA-2..hA+5, cols w_-2..w_+2
        if (interior) {
#pragma unroll
            for (int rrow = 0; rrow < 8; rrow++)
#pragma unroll
                for (int kw = 0; kw < 5; kw++)
                    tv[rrow * 5 + kw] = src[(hA - 2 + rrow) * Ww + (w_ - 2 + kw)];
        } else {
#pragma unroll
            for (int rrow = 0; rrow < 8; rrow++) {
                int y = hA - 2 + rrow;
#pragma unroll
                for (int kw = 0; kw < 5; kw++) {
                    int x = w_ - 2 + kw;
                    tv[rrow * 5 + kw] =
                        ((unsigned)y < (unsigned)Hh && (unsigned)x < (unsigned)Ww)
                            ? src[y * Ww + x] : 0.f;
                }
            }
        }
#pragma unroll
        for (int o = 0; o < 4; o++) {
            const float* wr = &wsm[(o * 4 + cl) * 25];
#pragma unroll
            for (int kh = 0; kh < 5; kh++)
#pragma unroll
                for (int kw = 0; kw < 5; kw++) {
                    float wv = wr[kh * 5 + kw];
                    acc[0 * 4 + o] = fmaf(wv, tv[(kh + 0) * 5 + kw], acc[0 * 4 + o]);
                    acc[1 * 4 + o] = fmaf(wv, tv[(kh + 1) * 5 + kw], acc[1 * 4 + o]);
                    acc[2 * 4 + o] = fmaf(wv, tv[(kh + 2) * 5 + kw], acc[2 * 4 + o]);
                    acc[3 * 4 + o] = fmaf(wv, tv[(kh + 3) * 5 + kw], acc[3 * 4 + o]);
                }
        }
    }
    float* dst = uf + (size_t)(b * C + g * 4) * HW;
#pragma unroll
    for (int o = 0; o < 4; o++)
#pragma unroll
        for (int px = 0; px < 4; px++)
            dst[o * HW + hw0 + px * Ww] = acc[px * 4 + o];
}

// helper for K7: one patch tap value (compile-time i -> static cl/kh/kw)
template <bool INT_>
DEVFN float tapval(const float* __restrict__ uf, int b, int g, int h, int w,
                   int i) {
    int cl = i / 9, r = i - cl * 9, kh = r / 3, kw = r - kh * 3;
    int y = h + kh - 1, x = w + kw - 1;
    const float* src = uf + (size_t)(b * C + g * 4 + cl) * HW;
    if (INT_) return src[y * Ww + x];
    return ((unsigned)y < (unsigned)Hh && (unsigned)x < (unsigned)Ww)
               ? src[y * Ww + x] : 0.f;
}

template <bool INT_>
DEVFN void load_patch_h2(const float* __restrict__ uf, int b, int g, int h,
                         int w, __half2* up) {
#pragma unroll
    for (int j = 0; j < 18; j++) {
        float f0 = tapval<INT_>(uf, b, g, h, w, 2 * j);
        float f1 = tapval<INT_>(uf, b, g, h, w, 2 * j + 1);
        up[j] = __floats2half2_rn(f0, f1);
    }
    up[18] = __floats2half2_rn(1.f, 0.f);
    up[19] = __floats2half2_rn(0.f, 0.f);
}

// K7: KBA + ga1 + residual uf + sca scaling -> xmid
// 64-thread blocks x 1600; thread = 8 pixels (NOTE-8: px-rate = Npx /
// LDS-cyc while LDS-bound). half2 weights in LDS (10.2KB); fp32 acc.
// VGPR ~220, capped 256 by __launch_bounds__(64,2).
__global__ __launch_bounds__(64, 2) void k7_kba(
        const float* __restrict__ att, const float* __restrict__ uf,
        const float* __restrict__ kbw, const float* __restrict__ kbb,
        const float* __restrict__ ga1, const float* __restrict__ sca,
        float* __restrict__ xmid) {
    __shared__ __half2 wsm[2560];      // [s][o][20]
    int bi  = blockIdx.x;              // 0..1599
    int g   = bi / 100;                // 0..15 (uniform)
    int pb  = bi % 100;
    int tid = threadIdx.x;             // 0..63

    for (int e = tid; e < 2560; e += 64) {
        int s = e / 80, r = e - s * 80, o = r / 20, j = r - o * 20;
        int i0 = 2 * j, i1 = i0 + 1;
        float f0 = (i0 < 36) ? kbw[(size_t)s * 2304 + g * 144 + o * 36 + i0]
                 : (i0 == 36 ? kbb[s * 64 + g * 4 + o] : 0.f);
        float f1 = (i1 < 36) ? kbw[(size_t)s * 2304 + g * 144 + o * 36 + i1]
                             : 0.f;
        wsm[e] = __floats2half2_rn(f0, f1);
    }
    __syncthreads();

    int p0  = pb * 512 + tid;          // 512 | HW -> b uniform per block
    int b   = p0 / HW;
    int hw0 = p0 - b * HW;

    __half2 U[8][20];
#pragma unroll
    for (int k = 0; k < 8; k++) {
        int hw = hw0 + 64 * k;
        int h = hw / Ww, w = hw - h * Ww;
        bool inter = (h >= 1 && h < Hh - 1 && w >= 1 && w < Ww - 1);
        if (inter) load_patch_h2<true>(uf, b, g, h, w, U[k]);
        else       load_patch_h2<false>(uf, b, g, h, w, U[k]);
    }

    const float* ap = att + (size_t)b * NSET * HW + hw0;
    float acc[8][4];
#pragma unroll
    for (int k = 0; k < 8; k++)
#pragma unroll
        for (int o = 0; o < 4; o++) acc[k][o] = 0.f;

#pragma unroll 1
    for (int s = 0; s < 32; s++) {
        float a[8];
#pragma unroll
        for (int k = 0; k < 8; k++) a[k] = ap[64 * k];
        ap += HW;
        const __half2* wp = &wsm[s * 80];
#pragma unroll
        for (int o = 0; o < 4; o++) {
            const __half2* wo = wp + o * 20;
            __half2 d[8];
#pragma unroll
            for (int k = 0; k < 8; k++) d[k] = __hmul2(wo[0], U[k][0]);
#pragma unroll
            for (int j = 1; j < 20; j++) {
                __half2 wv = wo[j];
#pragma unroll
                for (int k = 0; k < 8; k++) d[k] = __hfma2(wv, U[k][j], d[k]);
            }
#pragma unroll
            for (int k = 0; k < 8; k++)
                acc[k][o] = fmaf(a[k], __low2float(d[k]) + __high2float(d[k]),
                                 acc[k][o]);
        }
    }

#pragma unroll
    for (int o = 0; o < 4; o++) {
        int co = g * 4 + o;                    // uniform
        float ga = ga1[co];
        float sc = sca[b * 64 + co];
        const float* cf = uf + (size_t)(b * C + co) * HW;
        float* xm = xmid + (size_t)(b * C + co) * HW;
#pragma unroll
        for (int k = 0; k < 8; k++) {
            int hw = hw0 + 64 * k;
            xm[hw] = (acc[k][o] * ga + cf[hw]) * sc;
        }
    }
}

// K89: fused conv3+residual+LN2+FFN, half2 K-packed; 64-thread blocks.
__global__ __launch_bounds__(64, 2) void k89_ffn(
        const float* __restrict__ xmid, const float* __restrict__ inp,
        const float* __restrict__ conv3w, const float* __restrict__ conv3b,
        const float* __restrict__ beta, const float* __restrict__ lnw,
        const float* __restrict__ lnb, const float* __restrict__ w4,
        const float* __restrict__ b4, const float* __restrict__ w5,
        const float* __restrict__ b5, const float* __restrict__ gamma,
        float* __restrict__ out) {
    __shared__ __half2 H2[6144];
    __shared__ float F[256];   // b3[0,64) b4[64,192) b5[192,256)
    int tid = threadIdx.x;     // 0..63

    for (int e = tid; e < 2048; e += 64) {
        int cp = e >> 6, co = e & 63;
        H2[e] = __floats2half2_rn(conv3w[co * 64 + 2 * cp],
                                  conv3w[co * 64 + 2 * cp + 1]);
    }
    F[tid] = conv3b[tid];
    __syncthreads();

    int p = blockIdx.x * 64 + tid;
    int b = p / HW, hw = p % HW;
    const float* xc = xmid + (size_t)b * C * HW + hw;

    // conv3: half2 K-packed over ci
    __half2 a3[64];
#pragma unroll
    for (int co = 0; co < 64; co++) a3[co] = __floats2half2_rn(0.f, 0.f);
#pragma unroll 1
    for (int cp = 0; cp < 32; cp++) {
        float xv0 = xc[(size_t)(2 * cp) * HW];
        float xv1 = xc[(size_t)(2 * cp + 1) * HW];
        __half2 xv2 = __floats2half2_rn(xv0, xv1);
        const __half2* wrow = &H2[cp * 64];
#pragma unroll
        for (int co = 0; co < 64; co++)
            a3[co] = __hfma2(wrow[co], xv2, a3[co]);
    }
    const float* ic = inp + (size_t)b * C * HW + hw;
    float y[64];
#pragma unroll
    for (int co = 0; co < 64; co++) {
        float c3 = __low2float(a3[co]) + __high2float(a3[co]) + F[co];
        y[co] = ic[(size_t)co * HW] + c3 * beta[co];
    }

    // phase-2 staging
    __syncthreads();
    for (int e = tid; e < 4096; e += 64) {
        int j = e >> 5, cp = e & 31;
        H2[e] = __floats2half2_rn(w4[j * 64 + 2 * cp], w4[j * 64 + 2 * cp + 1]);
    }
    for (int e = tid; e < 2048; e += 64) {
        int t5 = e >> 6, co = e & 63;
        H2[4096 + e] = __floats2half2_rn(w5[co * 64 + 2 * t5],
                                         w5[co * 64 + 2 * t5 + 1]);
    }
    for (int e = tid; e < 128; e += 64) F[64 + e] = b4[e];
    F[192 + tid] = b5[tid];
    __syncthreads();

    // LN2
    float s = 0.f, s2 = 0.f;
#pragma unroll
    for (int c = 0; c < 64; c++) { s += y[c]; s2 += y[c] * y[c]; }
    float mu  = s * (1.f / 64.f);
    float var = fmaxf(s2 * (1.f / 64.f) - mu * mu, 0.f);
    float r   = rsqrtf(var + 1e-6f);
    __half2 v2[32], y2[32];
#pragma unroll
    for (int cp = 0; cp < 32; cp++) {
        float v0 = (y[2 * cp] - mu) * r * lnw[2 * cp] + lnb[2 * cp];
        float v1 = (y[2 * cp + 1] - mu) * r * lnw[2 * cp + 1] + lnb[2 * cp + 1];
        v2[cp] = __floats2half2_rn(v0, v1);
        y2[cp] = __floats2half2_rn(y[2 * cp], y[2 * cp + 1]);
    }

    __half2 a5[64];
#pragma unroll
    for (int co = 0; co < 64; co++) a5[co] = __floats2half2_rn(0.f, 0.f);

#pragma unroll 1
    for (int t5 = 0; t5 < 32; t5++) {
        int j0 = 2 * t5, j1 = j0 + 1;
        const __half2* r10 = &H2[j0 * 32];
        const __half2* r11 = &H2[j1 * 32];
        const __half2* r20 = &H2[(64 + j0) * 32];
        const __half2* r21 = &H2[(64 + j1) * 32];
        __half2 d10 = __hmul2(r10[0], v2[0]);
        __half2 d11 = __hmul2(r11[0], v2[0]);
        __half2 d20 = __hmul2(r20[0], v2[0]);
        __half2 d21 = __hmul2(r21[0], v2[0]);
#pragma unroll
        for (int cp = 1; cp < 32; cp++) {
            __half2 vv = v2[cp];
            d10 = __hfma2(r10[cp], vv, d10);
            d11 = __hfma2(r11[cp], vv, d11);
            d20 = __hfma2(r20[cp], vv, d20);
            d21 = __hfma2(r21[cp], vv, d21);
        }
        float t1_0 = __low2float(d10) + __high2float(d10) + F[64 + j0];
        float t1_1 = __low2float(d11) + __high2float(d11) + F[64 + j1];
        float t2_0 = __low2float(d20) + __high2float(d20) + F[128 + j0];
        float t2_1 = __low2float(d21) + __high2float(d21) + F[128 + j1];
        __half2 g2 = __floats2half2_rn(t1_0 * t2_0, t1_1 * t2_1);
        const __half2* w5r = &H2[4096 + t5 * 64];
#pragma unroll
        for (int co = 0; co < 64; co++)
            a5[co] = __hfma2(w5r[co], g2, a5[co]);
    }

    float* oc = out + (size_t)b * C * HW + hw;
#pragma unroll
    for (int co = 0; co < 64; co++) {
        float accf = __low2float(a5[co]) + __high2float(a5[co]) + F[192 + co];
        float yv = (co & 1) ? __high2float(y2[co >> 1]) : __low2float(y2[co >> 1]);
        oc[(size_t)co * HW] = yv + accf * gamma[co];
    }
}

extern "C" void kernel_launch(void* const* d_in, const int* in_sizes, int n_in,
                              void* d_out, int out_size, void* d_ws, size_t ws_size,
                              hipStream_t stream) {
    (void)in_sizes; (void)n_in; (void)out_size; (void)ws_size;

    const float* inp     = (const float*)d_in[0];
    const float* ln1_w   = (const float*)d_in[1];
    const float* ln1_b   = (const float*)d_in[2];
    const float* ln2_w   = (const float*)d_in[3];
    const float* ln2_b   = (const float*)d_in[4];
    const float* sca_w   = (const float*)d_in[5];
    const float* sca_b   = (const float*)d_in[6];
    const float* c11a_w  = (const float*)d_in[7];
    const float* c11a_b  = (const float*)d_in[8];
    const float* c11b_w  = (const float*)d_in[9];
    const float* c11b_b  = (const float*)d_in[10];
    const float* c2a_w   = (const float*)d_in[11];
    const float* c2a_b   = (const float*)d_in[12];
    const float* c2b_w   = (const float*)d_in[13];
    const float* c2b_b   = (const float*)d_in[14];
    const float* conv3_w = (const float*)d_in[15];
    const float* conv3_b = (const float*)d_in[16];
    const float* conv4_w = (const float*)d_in[17];
    const float* conv4_b = (const float*)d_in[18];
    const float* conv5_w = (const float*)d_in[19];
    const float* conv5_b = (const float*)d_in[20];
    const float* kb_w    = (const float*)d_in[21];
    const float* kb_b    = (const float*)d_in[22];
    const float* ga1     = (const float*)d_in[23];
    const float* attg    = (const float*)d_in[24];
    const float* beta    = (const float*)d_in[25];
    const float* gamma   = (const float*)d_in[26];

    // ---- ws arena (~33 MB) ----
    char* ws = (char*)d_ws;
    size_t off = 0;
    auto alloc = [&](size_t bytes) {
        void* r = ws + off;
        off += (bytes + 255) & ~(size_t)255;
        return r;
    };
    float* meanb = (float*)alloc(128 * 4);
    float* scab  = (float*)alloc(128 * 4);
    float* x1    = (float*)alloc((size_t)P * 64 * 4);   // 13.1 MB
    float* attb  = (float*)alloc((size_t)P * 32 * 4);   // 6.55 MB
    float* u1    = (float*)alloc((size_t)P * 64 * 4);   // 13.1 MB
    float* ufb   = x1;   // x1 dead after K45
    float* xmid  = u1;   // u1 dead after K6

    k1_ln1   <<<P / 64, 64, 0, stream>>>(inp, ln1_w, ln1_b, x1);
    k2_mean  <<<B * C, 256, 0, stream>>>(x1, meanb);
    k3_sca   <<<1, 128, 0, stream>>>(sca_w, sca_b, meanb, scab);
    k45_attu <<<P / 64, 64, 0, stream>>>(x1, c2a_w, c2a_b, c2b_w, c2b_b, attg,
                                         c11a_w, c11a_b, attb, u1);
    k6_uf    <<<1600, 128, 0, stream>>>(u1, c11b_w, c11b_b, ufb);
    k7_kba   <<<1600, 64, 0, stream>>>(attb, ufb, kb_w, kb_b, ga1, scab, xmid);
    k89_ffn  <<<P / 64, 64, 0, stream>>>(xmid, inp, conv3_w, conv3_b, beta,
                                         ln2_w, ln2_b, conv4_w, conv4_b,
                                         conv5_w, conv5_b, gamma, (float*)d_out);
}

// Round 13
// 451.587 us; speedup vs baseline: 1.3120x; 1.3120x over previous
//
#include <hip/hip_runtime.h>
#include <hip/hip_fp16.h>

#define DEVFN __device__ __forceinline__

constexpr int C   = 64;
constexpr int Hh  = 160, Ww = 160, HW = Hh * Ww;   // 25600
constexpr int B   = 2;
constexpr int P   = B * HW;                        // 51200
constexpr int NSET = 32;

typedef _Float16 f16;
typedef f16   f16x8 __attribute__((ext_vector_type(8)));
typedef float f32x4 __attribute__((ext_vector_type(4)));

// NOTE: __launch_bounds__ on every kernel (round 4: default caps VGPR at 64).
// NOTE-2 (round 5): register arrays must be statically indexed everywhere.
// NOTE-3 (round 6): >~48 uniform floats/iter cannot stream through SGPRs.
// NOTE-4 (round 7): >=4 independent FMA chains per loop body.
// NOTE-5 (round 8): LDS broadcast costs ~12cyc/b128 on the per-CU LDS pipe.
// NOTE-6 (round 9): keep enough waves; shrink per-thread state via f16.
// NOTE-7 (round 10): f16 K-packing halves LDS bytes + inst count.
// NOTE-8 (round 11): LDS-bound loops scale with px-per-weight-read.
// NOTE-9 (round 12, REVISED): 64-thread blocks multiply per-block LDS
// staging cost 4x; keep 256-thread blocks for kernels with big LDS stages.
// 8px/thread without the VGPRs to back it (compiler gave 108) regresses.
// NOTE-10 (round 13): VALU f16 GEMMs are stuck at ~2048 LDS-broadcast half2
// per pixel -> ~50% VALU ceiling. MFMA with A-frags (weights) in REGISTERS
// removes LDS from the inner loop entirely. Fold scale vectors (beta, lnw,
// gamma) into A-frags; biases into per-lane constants. C-layout:
// col=lane&15(=pixel), row=(lane>>4)*4+reg; A: m=lane&15, k=quad*8+j;
// B: n=lane&15, k=quad*8+j. C->B transpose needs an LDS round-trip.

// K1: LayerNorm over channels per pixel
__global__ __launch_bounds__(256) void k1_ln1(
        const float* __restrict__ inp, const float* __restrict__ lnw,
        const float* __restrict__ lnb, float* __restrict__ x1) {
    int p = blockIdx.x * 256 + threadIdx.x;
    int b = p / HW, hw = p % HW;
    const float* src = inp + (size_t)b * C * HW + hw;
    float v[64];
    float s = 0.f, s2 = 0.f;
#pragma unroll
    for (int c = 0; c < 64; c++) {
        float f = src[c * HW];
        v[c] = f; s += f; s2 += f * f;
    }
    float mu  = s * (1.f / 64.f);
    float var = fmaxf(s2 * (1.f / 64.f) - mu * mu, 0.f);
    float r   = rsqrtf(var + 1e-6f);
    float* dst = x1 + (size_t)b * C * HW + hw;
#pragma unroll
    for (int c = 0; c < 64; c++)
        dst[c * HW] = (v[c] - mu) * r * lnw[c] + lnb[c];
}

// K2: spatial mean of x1 per (b,c)
__global__ __launch_bounds__(256) void k2_mean(
        const float* __restrict__ x1, float* __restrict__ meanb) {
    int bc = blockIdx.x;                         // 0..127
    const float* src = x1 + (size_t)bc * HW;
    float s = 0.f;
    for (int i = threadIdx.x; i < HW; i += 256) s += src[i];
#pragma unroll
    for (int o = 32; o > 0; o >>= 1) s += __shfl_down(s, o);
    __shared__ float red[4];
    if ((threadIdx.x & 63) == 0) red[threadIdx.x >> 6] = s;
    __syncthreads();
    if (threadIdx.x == 0)
        meanb[bc] = (red[0] + red[1] + red[2] + red[3]) * (1.f / HW);
}

// K3: sca = sca_w @ mean + sca_b   [B,64]
__global__ __launch_bounds__(256) void k3_sca(
        const float* __restrict__ scaw, const float* __restrict__ scab_,
        const float* __restrict__ meanb, float* __restrict__ sca) {
    int t = threadIdx.x;
    if (t >= 128) return;
    int b = t >> 6, c = t & 63;
    float acc = scab_[c];
#pragma unroll
    for (int k = 0; k < 64; k++)
        acc = fmaf(scaw[c * 64 + k], meanb[b * 64 + k], acc);
    sca[t] = acc;
}

// helper: 3x3 grouped conv taps (groups=32, 2 in-ch per out-ch)
template <bool INT_>
DEVFN void att_taps(const float* __restrict__ xb, int h, int w,
                    const float* c2aw, const float* c2ab, float* t) {
#pragma unroll
    for (int o = 0; o < 32; o++) {
        float acc = c2ab[o];
#pragma unroll
        for (int k = 0; k < 2; k++) {
            const float* xc = xb + (size_t)(2 * o + k) * HW;
            const float* wr = c2aw + (o * 2 + k) * 9;
#pragma unroll
            for (int kh = 0; kh < 3; kh++) {
                int y = h + kh - 1;
#pragma unroll
                for (int kw = 0; kw < 3; kw++) {
                    int x = w + kw - 1;
                    if (INT_ || ((unsigned)y < (unsigned)Hh && (unsigned)x < (unsigned)Ww))
                        acc = fmaf(wr[kh * 3 + kw], xc[y * Ww + x], acc);
                }
            }
        }
        t[o] = acc;
    }
}

// K45: fused k4 (att) + k5 (u1); round-11 version (256-thread blocks).
__global__ __launch_bounds__(256) void k45_attu(
        const float* __restrict__ x1, const float* __restrict__ c2aw,
        const float* __restrict__ c2ab, const float* __restrict__ c2bw,
        const float* __restrict__ c2bb, const float* __restrict__ attg,
        const float* __restrict__ c11aw, const float* __restrict__ c11ab,
        float* __restrict__ att, float* __restrict__ u1) {
    __shared__ __half2 W2[2048];
    __shared__ float Wf[1248];
    int tid = threadIdx.x;
    for (int e = tid; e < 2048; e += 256) {
        int cp = e >> 6, co = e & 63;
        W2[e] = __floats2half2_rn(c11aw[co * 64 + 2 * cp],
                                  c11aw[co * 64 + 2 * cp + 1]);
    }
    for (int e = tid; e < 1248; e += 256) {
        float v;
        if (e < 64)        v = c11ab[e];
        else if (e < 640)  v = c2aw[e - 64];
        else if (e < 672)  v = c2ab[e - 640];
        else if (e < 1184) v = c2bw[e - 672];
        else if (e < 1216) v = c2bb[e - 1184];
        else               v = attg[e - 1216];
        Wf[e] = v;
    }
    __syncthreads();

    int p = blockIdx.x * 256 + tid;
    int b = p / HW, hw = p % HW, h = hw / Ww, w = hw % Ww;
    const float* xb = x1 + (size_t)b * C * HW;

    float t[32];
    bool interior = (h >= 1 && h < Hh - 1 && w >= 1 && w < Ww - 1);
    if (interior) att_taps<true>(xb, h, w, &Wf[64], &Wf[640], t);
    else          att_taps<false>(xb, h, w, &Wf[64], &Wf[640], t);
    float g[16];
#pragma unroll
    for (int c = 0; c < 16; c++) g[c] = t[c] * t[c + 16];
    float* adst = att + (size_t)b * NSET * HW + hw;
#pragma unroll 1
    for (int s = 0; s < 32; s++) {
        float acc = Wf[1184 + s];
        const float* wr = &Wf[672 + s * 16];
#pragma unroll
        for (int c = 0; c < 16; c++) acc = fmaf(wr[c], g[c], acc);
        adst[(size_t)s * HW] = acc * Wf[1216 + s];
    }

    __half2 acc2[64];
#pragma unroll
    for (int co = 0; co < 64; co++) acc2[co] = __floats2half2_rn(0.f, 0.f);
    const float* xc = xb + hw;
#pragma unroll 1
    for (int cp = 0; cp < 32; cp++) {
        float xv0 = xc[(size_t)(2 * cp) * HW];
        float xv1 = xc[(size_t)(2 * cp + 1) * HW];
        __half2 xv2 = __floats2half2_rn(xv0, xv1);
        const __half2* wrow = &W2[cp * 64];
#pragma unroll
        for (int co = 0; co < 64; co++)
            acc2[co] = __hfma2(wrow[co], xv2, acc2[co]);
    }
    float* dst = u1 + (size_t)b * C * HW + hw;
#pragma unroll
    for (int co = 0; co < 64; co++)
        dst[co * HW] = __low2float(acc2[co]) + __high2float(acc2[co]) + Wf[co];
}

// K6: uf = 5x5 grouped conv (groups=16) of u1, pad=2. Round-11 version.
__global__ __launch_bounds__(128) void k6_uf(
        const float* __restrict__ u1, const float* __restrict__ w,
        const float* __restrict__ bias, float* __restrict__ uf) {
    __shared__ float wsm[404];
    int blk = blockIdx.x;              // 0..1599
    int g   = blk / 100;               // 0..15 uniform
    int ublk = blk % 100;
    int tid = threadIdx.x;
    for (int e = tid; e < 400; e += 128) {
        int o = e / 100, rest = e - o * 100, cl = rest / 25, tp = rest - cl * 25;
        wsm[e] = w[(((g * 4 + o) * 4) + cl) * 25 + tp];
    }
    if (tid < 4) wsm[400 + tid] = bias[g * 4 + tid];
    __syncthreads();

    int unit = ublk * 128 + tid;
    int b  = unit / (HW / 4);
    int rr = unit - b * (HW / 4);
    int r4 = rr / Ww, w_ = rr - r4 * Ww;
    int hA = r4 * 4;
    int hw0 = hA * Ww + w_;
    bool interior = (w_ >= 2 && w_ < Ww - 2 && r4 >= 1 && r4 <= 38);

    float acc[16];
#pragma unroll
    for (int i = 0; i < 16; i++) acc[i] = wsm[400 + (i & 3)];

#pragma unroll 1
    for (int cl = 0; cl < 4; cl++) {
        const float* src = u1 + (size_t)(b * C + g * 4 + cl) * HW;
        float tv[40];
        if (interior) {
#pragma unroll
            for (int rrow = 0; rrow < 8; rrow++)
#pragma unroll
                for (int kw = 0; kw < 5; kw++)
                    tv[rrow * 5 + kw] = src[(hA - 2 + rrow) * Ww + (w_ - 2 + kw)];
        } else {
#pragma unroll
            for (int rrow = 0; rrow < 8; rrow++) {
                int y = hA - 2 + rrow;
#pragma unroll
                for (int kw = 0; kw < 5; kw++) {
                    int x = w_ - 2 + kw;
                    tv[rrow * 5 + kw] =
                        ((unsigned)y < (unsigned)Hh && (unsigned)x < (unsigned)Ww)
                            ? src[y * Ww + x] : 0.f;
                }
            }
        }
#pragma unroll
        for (int o = 0; o < 4; o++) {
            const float* wr = &wsm[(o * 4 + cl) * 25];
#pragma unroll
            for (int kh = 0; kh < 5; kh++)
#pragma unroll
                for (int kw = 0; kw < 5; kw++) {
                    float wv = wr[kh * 5 + kw];
                    acc[0 * 4 + o] = fmaf(wv, tv[(kh + 0) * 5 + kw], acc[0 * 4 + o]);
                    acc[1 * 4 + o] = fmaf(wv, tv[(kh + 1) * 5 + kw], acc[1 * 4 + o]);
                    acc[2 * 4 + o] = fmaf(wv, tv[(kh + 2) * 5 + kw], acc[2 * 4 + o]);
                    acc[3 * 4 + o] = fmaf(wv, tv[(kh + 3) * 5 + kw], acc[3 * 4 + o]);
                }
        }
    }
    float* dst = uf + (size_t)(b * C + g * 4) * HW;
#pragma unroll
    for (int o = 0; o < 4; o++)
#pragma unroll
        for (int px = 0; px < 4; px++)
            dst[o * HW + hw0 + px * Ww] = acc[px * 4 + o];
}

// helpers for K7 (round-11 version)
template <bool INT_>
DEVFN float tapval(const float* __restrict__ uf, int b, int g, int h, int w,
                   int i) {
    int cl = i / 9, r = i - cl * 9, kh = r / 3, kw = r - kh * 3;
    int y = h + kh - 1, x = w + kw - 1;
    const float* src = uf + (size_t)(b * C + g * 4 + cl) * HW;
    if (INT_) return src[y * Ww + x];
    return ((unsigned)y < (unsigned)Hh && (unsigned)x < (unsigned)Ww)
               ? src[y * Ww + x] : 0.f;
}

template <bool INT_>
DEVFN void load_patch_h2(const float* __restrict__ uf, int b, int g, int h,
                         int w, __half2* up) {
#pragma unroll
    for (int j = 0; j < 18; j++) {
        float f0 = tapval<INT_>(uf, b, g, h, w, 2 * j);
        float f1 = tapval<INT_>(uf, b, g, h, w, 2 * j + 1);
        up[j] = __floats2half2_rn(f0, f1);
    }
    up[18] = __floats2half2_rn(1.f, 0.f);
    up[19] = __floats2half2_rn(0.f, 0.f);
}

// K7: KBA (round-11 version: 128-thread blocks, 4 px/thread, half2 LDS)
__global__ __launch_bounds__(128) void k7_kba(
        const float* __restrict__ att, const float* __restrict__ uf,
        const float* __restrict__ kbw, const float* __restrict__ kbb,
        const float* __restrict__ ga1, const float* __restrict__ sca,
        float* __restrict__ xmid) {
    __shared__ __half2 wsm[2560];      // [s][o][20]
    int bi  = blockIdx.x;              // 0..1599
    int g   = bi / 100;                // 0..15 (uniform)
    int pb  = bi % 100;
    int tid = threadIdx.x;

    for (int e = tid; e < 2560; e += 128) {
        int s = e / 80, r = e - s * 80, o = r / 20, j = r - o * 20;
        int i0 = 2 * j, i1 = i0 + 1;
        float f0 = (i0 < 36) ? kbw[(size_t)s * 2304 + g * 144 + o * 36 + i0]
                 : (i0 == 36 ? kbb[s * 64 + g * 4 + o] : 0.f);
        float f1 = (i1 < 36) ? kbw[(size_t)s * 2304 + g * 144 + o * 36 + i1]
                             : 0.f;
        wsm[e] = __floats2half2_rn(f0, f1);
    }
    __syncthreads();

    int pA = pb * 512 + tid;           // 512 | HW -> b uniform per block
    int b  = pA / HW;
    int hwA = pA - b * HW;
    int hwB = hwA + 128, hwC = hwA + 256, hwD = hwA + 384;
    int hA = hwA / Ww, wA = hwA - hA * Ww;
    int hB = hwB / Ww, wB = hwB - hB * Ww;
    int hC = hwC / Ww, wC = hwC - hC * Ww;
    int hD = hwD / Ww, wD = hwD - hD * Ww;

    __half2 uA[20], uB[20], uC[20], uD[20];
    bool iA = (hA >= 1 && hA < Hh - 1 && wA >= 1 && wA < Ww - 1);
    bool iB = (hB >= 1 && hB < Hh - 1 && wB >= 1 && wB < Ww - 1);
    bool iC = (hC >= 1 && hC < Hh - 1 && wC >= 1 && wC < Ww - 1);
    bool iD = (hD >= 1 && hD < Hh - 1 && wD >= 1 && wD < Ww - 1);
    if (iA) load_patch_h2<true>(uf, b, g, hA, wA, uA);
    else    load_patch_h2<false>(uf, b, g, hA, wA, uA);
    if (iB) load_patch_h2<true>(uf, b, g, hB, wB, uB);
    else    load_patch_h2<false>(uf, b, g, hB, wB, uB);
    if (iC) load_patch_h2<true>(uf, b, g, hC, wC, uC);
    else    load_patch_h2<false>(uf, b, g, hC, wC, uC);
    if (iD) load_patch_h2<true>(uf, b, g, hD, wD, uD);
    else    load_patch_h2<false>(uf, b, g, hD, wD, uD);

    const float* ap = att + (size_t)b * NSET * HW + hwA;

    float acc0[4] = {0.f, 0.f, 0.f, 0.f};
    float acc1[4] = {0.f, 0.f, 0.f, 0.f};
    float acc2[4] = {0.f, 0.f, 0.f, 0.f};
    float acc3[4] = {0.f, 0.f, 0.f, 0.f};

#pragma unroll 1
    for (int s = 0; s < 32; s++) {
        float a0 = ap[0], a1 = ap[128], a2 = ap[256], a3 = ap[384];
        ap += HW;
        const __half2* wp = &wsm[s * 80];
#pragma unroll
        for (int o = 0; o < 4; o++) {
            const __half2* wo = wp + o * 20;
            __half2 d0 = __hmul2(wo[0], uA[0]);
            __half2 d1 = __hmul2(wo[0], uB[0]);
            __half2 d2 = __hmul2(wo[0], uC[0]);
            __half2 d3 = __hmul2(wo[0], uD[0]);
#pragma unroll
            for (int j = 1; j < 20; j++) {
                __half2 wv = wo[j];
                d0 = __hfma2(wv, uA[j], d0);
                d1 = __hfma2(wv, uB[j], d1);
                d2 = __hfma2(wv, uC[j], d2);
                d3 = __hfma2(wv, uD[j], d3);
            }
            acc0[o] = fmaf(a0, __low2float(d0) + __high2float(d0), acc0[o]);
            acc1[o] = fmaf(a1, __low2float(d1) + __high2float(d1), acc1[o]);
            acc2[o] = fmaf(a2, __low2float(d2) + __high2float(d2), acc2[o]);
            acc3[o] = fmaf(a3, __low2float(d3) + __high2float(d3), acc3[o]);
        }
    }

#pragma unroll
    for (int o = 0; o < 4; o++) {
        int co = g * 4 + o;                    // uniform
        float ga = ga1[co];
        float sc = sca[b * 64 + co];
        const float* cf = uf + (size_t)(b * C + co) * HW;
        float* xm = xmid + (size_t)(b * C + co) * HW;
        xm[hwA] = (acc0[o] * ga + cf[hwA]) * sc;
        xm[hwB] = (acc1[o] * ga + cf[hwB]) * sc;
        xm[hwC] = (acc2[o] * ga + cf[hwC]) * sc;
        xm[hwD] = (acc3[o] * ga + cf[hwD]) * sc;
    }
}

// K89-MFMA: conv3+residual+LN2+FFN via v_mfma_f32_16x16x32_f16 (NOTE-10).
// Per wave: A-frags for W3*beta (4x2), W4*lnw (8x2), W5*gamma (4x2) loaded
// once. Per 16-px tile: conv3 MFMA -> y(f32 regs) -> LN stats via shfl_xor
// (mu,r are lane-scalars since a lane's col = its pixel) -> (y-mu) f16 ->
// LDS transpose -> conv4 MFMA -> gate -> LDS transpose -> conv5 MFMA ->
// out = y + acc + b5*gamma. Biases folded: C3i=b3*beta, C4=b4+W4@lnb, B5G.
__global__ __launch_bounds__(64) void k89_mfma(
        const float* __restrict__ xmid, const float* __restrict__ inp,
        const float* __restrict__ conv3w, const float* __restrict__ conv3b,
        const float* __restrict__ beta, const float* __restrict__ lnw,
        const float* __restrict__ lnb, const float* __restrict__ w4,
        const float* __restrict__ b4, const float* __restrict__ w5,
        const float* __restrict__ b5, const float* __restrict__ gamma,
        float* __restrict__ out) {
    __shared__ float CONST[256];   // C3i[0,64) C4[64,192) B5G[192,256)
    __shared__ f16 TBUF[16 * 72];  // [n][k], stride 72 (16B-aligned rows)

    int tid = threadIdx.x;         // 0..63
    int m = tid & 15, q = tid >> 4;

    // --- per-block constant precompute ---
    {
        float k4a = 0.f, k4b = 0.f;
#pragma unroll 1
        for (int ci = 0; ci < 64; ci++) {
            float lb = lnb[ci];
            k4a = fmaf(w4[tid * 64 + ci], lb, k4a);
            k4b = fmaf(w4[(tid + 64) * 64 + ci], lb, k4b);
        }
        CONST[tid] = conv3b[tid] * beta[tid];
        CONST[64 + tid] = k4a + b4[tid];
        CONST[128 + tid] = k4b + b4[tid + 64];
        CONST[192 + tid] = b5[tid] * gamma[tid];
    }

    // --- A-fragments (weights folded with scale vectors) ---
    f16x8 A3[4][2], A4[8][2], A5[4][2];
#pragma unroll
    for (int mt = 0; mt < 4; mt++) {
        int co = mt * 16 + m;
        float be = beta[co], gm = gamma[co];
#pragma unroll
        for (int c = 0; c < 2; c++)
#pragma unroll
            for (int j = 0; j < 8; j++) {
                int k = c * 32 + q * 8 + j;
                A3[mt][c][j] = (f16)(conv3w[co * 64 + k] * be);
                A5[mt][c][j] = (f16)(w5[co * 64 + k] * gm);
            }
    }
#pragma unroll
    for (int mt = 0; mt < 8; mt++) {
        int jr = mt * 16 + m;
#pragma unroll
        for (int c = 0; c < 2; c++)
#pragma unroll
            for (int j = 0; j < 8; j++) {
                int k = c * 32 + q * 8 + j;
                A4[mt][c][j] = (f16)(w4[jr * 64 + k] * lnw[k]);
            }
    }
    __syncthreads();

    // hoist lane constants (tile-invariant)
    float c3i[16], b5g[16];
#pragma unroll
    for (int mt = 0; mt < 4; mt++)
#pragma unroll
        for (int r = 0; r < 4; r++) {
            c3i[mt * 4 + r] = CONST[mt * 16 + q * 4 + r];
            b5g[mt * 4 + r] = CONST[192 + mt * 16 + q * 4 + r];
        }

    const f32x4 zero = {0.f, 0.f, 0.f, 0.f};

#pragma unroll 1
    for (int tile = blockIdx.x; tile < P / 16; tile += gridDim.x) {
        int px0 = tile * 16;
        int b = px0 / HW;
        int hw0 = px0 - b * HW;
        const float* xb = xmid + (size_t)b * C * HW + hw0 + m;
        const float* ib = inp + (size_t)b * C * HW + hw0 + m;
        float* ob = out + (size_t)b * C * HW + hw0 + m;

        // B-frags of xmid (f32 -> f16)
        f16x8 BX[2];
#pragma unroll
        for (int c = 0; c < 2; c++)
#pragma unroll
            for (int j = 0; j < 8; j++)
                BX[c][j] = (f16)xb[(size_t)(c * 32 + q * 8 + j) * HW];

        // conv3
        f32x4 accY[4];
#pragma unroll
        for (int mt = 0; mt < 4; mt++) {
            accY[mt] = __builtin_amdgcn_mfma_f32_16x16x32_f16(A3[mt][0], BX[0], zero, 0, 0, 0);
            accY[mt] = __builtin_amdgcn_mfma_f32_16x16x32_f16(A3[mt][1], BX[1], accY[mt], 0, 0, 0);
        }
        float y[16];
#pragma unroll
        for (int mt = 0; mt < 4; mt++)
#pragma unroll
            for (int r = 0; r < 4; r++) {
                int co = mt * 16 + q * 4 + r;
                y[mt * 4 + r] = ib[(size_t)co * HW] + accY[mt][r] + c3i[mt * 4 + r];
            }

        // LN2 stats (lane's 16 values all belong to pixel col = m)
        float s = 0.f, s2 = 0.f;
#pragma unroll
        for (int i = 0; i < 16; i++) { s += y[i]; s2 += y[i] * y[i]; }
        s  += __shfl_xor(s, 16);  s  += __shfl_xor(s, 32);
        s2 += __shfl_xor(s2, 16); s2 += __shfl_xor(s2, 32);
        float mu  = s * (1.f / 64.f);
        float var = fmaxf(s2 * (1.f / 64.f) - mu * mu, 0.f);
        float rr  = rsqrtf(var + 1e-6f);

        // transpose (y-mu) to B-layout via LDS
#pragma unroll
        for (int mt = 0; mt < 4; mt++)
#pragma unroll
            for (int r = 0; r < 4; r++)
                TBUF[m * 72 + mt * 16 + q * 4 + r] = (f16)(y[mt * 4 + r] - mu);
        __syncthreads();
        f16x8 BV[2];
#pragma unroll
        for (int c = 0; c < 2; c++)
#pragma unroll
            for (int j = 0; j < 8; j++)
                BV[c][j] = TBUF[m * 72 + c * 32 + q * 8 + j];

        // conv4 (128 rows)
        f32x4 accT[8];
#pragma unroll
        for (int mt = 0; mt < 8; mt++) {
            accT[mt] = __builtin_amdgcn_mfma_f32_16x16x32_f16(A4[mt][0], BV[0], zero, 0, 0, 0);
            accT[mt] = __builtin_amdgcn_mfma_f32_16x16x32_f16(A4[mt][1], BV[1], accT[mt], 0, 0, 0);
        }
        __syncthreads();   // all reads of TBUF done before overwrite

        // gate: t1 (rows 0..63) * t2 (rows 64..127); write g to TBUF
#pragma unroll
        for (int mt = 0; mt < 4; mt++)
#pragma unroll
            for (int r = 0; r < 4; r++) {
                int j = mt * 16 + q * 4 + r;
                float t1 = rr * accT[mt][r] + CONST[64 + j];
                float t2 = rr * accT[mt + 4][r] + CONST[128 + j];
                TBUF[m * 72 + j] = (f16)(t1 * t2);
            }
        __syncthreads();
        f16x8 BG[2];
#pragma unroll
        for (int c = 0; c < 2; c++)
#pragma unroll
            for (int j = 0; j < 8; j++)
                BG[c][j] = TBUF[m * 72 + c * 32 + q * 8 + j];
        __syncthreads();   // reads done before next tile overwrites

        // conv5
        f32x4 accO[4];
#pragma unroll
        for (int mt = 0; mt < 4; mt++) {
            accO[mt] = __builtin_amdgcn_mfma_f32_16x16x32_f16(A5[mt][0], BG[0], zero, 0, 0, 0);
            accO[mt] = __builtin_amdgcn_mfma_f32_16x16x32_f16(A5[mt][1], BG[1], accO[mt], 0, 0, 0);
        }
#pragma unroll
        for (int mt = 0; mt < 4; mt++)
#pragma unroll
            for (int r = 0; r < 4; r++) {
                int co = mt * 16 + q * 4 + r;
                ob[(size_t)co * HW] = y[mt * 4 + r] + accO[mt][r] + b5g[mt * 4 + r];
            }
    }
}

extern "C" void kernel_launch(void* const* d_in, const int* in_sizes, int n_in,
                              void* d_out, int out_size, void* d_ws, size_t ws_size,
                              hipStream_t stream) {
    (void)in_sizes; (void)n_in; (void)out_size; (void)ws_size;

    const float* inp     = (const float*)d_in[0];
    const float* ln1_w   = (const float*)d_in[1];
    const float* ln1_b   = (const float*)d_in[2];
    const float* ln2_w   = (const float*)d_in[3];
    const float* ln2_b   = (const float*)d_in[4];
    const float* sca_w   = (const float*)d_in[5];
    const float* sca_b   = (const float*)d_in[6];
    const float* c11a_w  = (const float*)d_in[7];
    const float* c11a_b  = (const float*)d_in[8];
    const float* c11b_w  = (const float*)d_in[9];
    const float* c11b_b  = (const float*)d_in[10];
    const float* c2a_w   = (const float*)d_in[11];
    const float* c2a_b   = (const float*)d_in[12];
    const float* c2b_w   = (const float*)d_in[13];
    const float* c2b_b   = (const float*)d_in[14];
    const float* conv3_w = (const float*)d_in[15];
    const float* conv3_b = (const float*)d_in[16];
    const float* conv4_w = (const float*)d_in[17];
    const float* conv4_b = (const float*)d_in[18];
    const float* conv5_w = (const float*)d_in[19];
    const float* conv5_b = (const float*)d_in[20];
    const float* kb_w    = (const float*)d_in[21];
    const float* kb_b    = (const float*)d_in[22];
    const float* ga1     = (const float*)d_in[23];
    const float* attg    = (const float*)d_in[24];
    const float* beta    = (const float*)d_in[25];
    const float* gamma   = (const float*)d_in[26];

    // ---- ws arena (~33 MB) ----
    char* ws = (char*)d_ws;
    size_t off = 0;
    auto alloc = [&](size_t bytes) {
        void* r = ws + off;
        off += (bytes + 255) & ~(size_t)255;
        return r;
    };
    float* meanb = (float*)alloc(128 * 4);
    float* scab  = (float*)alloc(128 * 4);
    float* x1    = (float*)alloc((size_t)P * 64 * 4);   // 13.1 MB
    float* attb  = (float*)alloc((size_t)P * 32 * 4);   // 6.55 MB
    float* u1    = (float*)alloc((size_t)P * 64 * 4);   // 13.1 MB
    float* ufb   = x1;   // x1 dead after K45
    float* xmid  = u1;   // u1 dead after K6

    k1_ln1   <<<P / 256, 256, 0, stream>>>(inp, ln1_w, ln1_b, x1);
    k2_mean  <<<B * C, 256, 0, stream>>>(x1, meanb);
    k3_sca   <<<1, 128, 0, stream>>>(sca_w, sca_b, meanb, scab);
    k45_attu <<<P / 256, 256, 0, stream>>>(x1, c2a_w, c2a_b, c2b_w, c2b_b, attg,
                                           c11a_w, c11a_b, attb, u1);
    k6_uf    <<<1600, 128, 0, stream>>>(u1, c11b_w, c11b_b, ufb);
    k7_kba   <<<1600, 128, 0, stream>>>(attb, ufb, kb_w, kb_b, ga1, scab, xmid);
    k89_mfma <<<800, 64, 0, stream>>>(xmid, inp, conv3_w, conv3_b, beta,
                                      ln2_w, ln2_b, conv4_w, conv4_b,
                                      conv5_w, conv5_b, gamma, (float*)d_out);
}